// Round 6
// baseline (265.792 us; speedup 1.0000x reference)
//
#include <hip/hip_runtime.h>
#include <cmath>
#include <complex>

#define T_TAB 4096
#define G_TAB 8
#define NN 16384
#define CH 16

// ---------------- CG tables (exact host-side port of the reference) ----------------
struct CGPack {
  float c000[1];
  float c110[9];
  float c220[25];
  float c330[49];
  float c011[9];
  float c101[9];
  float c111[27];
  float c121[45];
  float c211[45];
  float c221[75];
  float c231[105];
  float c321[105];
  float c331[147];
};

static double factd(int n){ double r=1.0; for(int i=2;i<=n;++i) r*=(double)i; return r; }

static double cg_coef(int j1,int m1,int j2,int m2,int j3,int m3){
  double pref = sqrt((2.0*j3+1.0)*factd(j3+j1-j2)*factd(j3-j1+j2)*factd(j1+j2-j3)/factd(j1+j2+j3+1));
  pref *= sqrt(factd(j3+m3)*factd(j3-m3)*factd(j1-m1)*factd(j1+m1)*factd(j2-m2)*factd(j2+m2));
  double s=0.0;
  for(int k=0;k<=j1+j2-j3;++k){
    int a0=k,a1=j1+j2-j3-k,a2=j1-m1-k,a3=j2+m2-k,a4=j3-j2+m1+k,a5=j3-j1-m2+k;
    if(a0<0||a1<0||a2<0||a3<0||a4<0||a5<0) continue;
    double d=factd(a0)*factd(a1)*factd(a2)*factd(a3)*factd(a4)*factd(a5);
    s += ((k&1)?-1.0:1.0)/d;
  }
  return pref*s;
}

static void u_fill(int l, std::complex<double> U[7][7]){
  for(int i=0;i<7;++i) for(int j=0;j<7;++j) U[i][j]=std::complex<double>(0.0,0.0);
  const double is2 = 1.0/sqrt(2.0);
  U[l][l]=1.0;
  for(int m=1;m<=l;++m){
    double sgn = (m&1)?-1.0:1.0;
    U[l+m][l+m] = sgn*is2;
    U[l+m][l-m] = is2;
    U[l-m][l-m] = std::complex<double>(0.0, is2);
    U[l-m][l+m] = std::complex<double>(0.0, -sgn*is2);
  }
}

static void cg_fill(int l1,int l2,int l3, float* out){
  int n1=2*l1+1,n2=2*l2+1,n3=2*l3+1;
  double Cc[7][7][7];
  for(int a=0;a<7;++a)for(int b=0;b<7;++b)for(int c=0;c<7;++c) Cc[a][b][c]=0.0;
  for(int m1=-l1;m1<=l1;++m1)
    for(int m2=-l2;m2<=l2;++m2){
      int m3=m1+m2;
      if(m3>=-l3&&m3<=l3) Cc[m1+l1][m2+l2][m3+l3]=cg_coef(l1,m1,l2,m2,l3,m3);
    }
  std::complex<double> U1[7][7],U2[7][7],U3[7][7];
  u_fill(l1,U1); u_fill(l2,U2); u_fill(l3,U3);
  std::complex<double> Cr[343];
  double sre=0.0,sim=0.0;
  for(int a=0;a<n1;++a)for(int b=0;b<n2;++b)for(int c=0;c<n3;++c){
    std::complex<double> acc(0.0,0.0);
    for(int u=0;u<n1;++u)for(int v=0;v<n2;++v)for(int w=0;w<n3;++w){
      double cc=Cc[u][v][w];
      if(cc==0.0) continue;
      acc += U1[a][u]*U2[b][v]*std::conj(U3[c][w])*cc;
    }
    Cr[(a*n2+b)*n3+c]=acc;
    sre+=fabs(acc.real()); sim+=fabs(acc.imag());
  }
  bool useim = sim>sre;
  for(int idx=0;idx<n1*n2*n3;++idx) out[idx]=(float)(useim?Cr[idx].imag():Cr[idx].real());
}

static void build_cg(CGPack& P){
  cg_fill(0,0,0,P.c000);
  cg_fill(1,1,0,P.c110);
  cg_fill(2,2,0,P.c220);
  cg_fill(3,3,0,P.c330);
  cg_fill(0,1,1,P.c011);
  cg_fill(1,0,1,P.c101);
  cg_fill(1,1,1,P.c111);
  cg_fill(1,2,1,P.c121);
  cg_fill(2,1,1,P.c211);
  cg_fill(2,2,1,P.c221);
  cg_fill(2,3,1,P.c231);
  cg_fill(3,2,1,P.c321);
  cg_fill(3,3,1,P.c331);
}

// ---------------- device helpers ----------------
__device__ __forceinline__ float soh(float r, float c){
  float d = (r - c) * 2.0f;
  float d2 = d*d;
  return (d2 < 1.0f) ? 1.14136f * expf(2.0f + 1.0f/(d2-1.0f)) : 0.0f;
}

// Per-lane weight schedule: lane ℓ, sub-index q (0..7) -> (column in [0,272) or -1, LDS slot).
// Slot 31 is a guaranteed-zero slot.
__device__ __forceinline__ void lane_sched(int lane, int q, int& col, int& slot){
  col = -1; slot = 31;
  if (lane < 16){
    int s = q >> 2, qq = q & 3;
    int a = 2*lane + s;                 // scalar output index 0..31
    const int base0[4] = {0, 64, 144, 224};
    col = base0[qq] + a; slot = qq;
  } else if (lane < 40){
    int idx = lane-16, u = idx/3, k = idx-3*u;
    const int wb[6] = {32,48,112,128,192,208};
    const int sb[6] = {4,7,10,13,16,19};
    if (q < 6){ col = wb[q]+u; slot = sb[q]+k; }
  } else if (lane < 52){
    int m = lane-40;
    int c0 = (q < 4) ? 2*m : 2*m+1;
    int u = c0/3, k = c0-3*u;
    int qq = (q < 4) ? q : q-4;
    if (qq < 3){
      const int wb[3] = {96,176,256};
      const int sb[3] = {22,25,28};
      col = wb[qq]+u; slot = sb[qq]+k;
    }
  }
}

// ---------------- radial MLP lookup table: tab[T_TAB][336] ----------------
__global__ __launch_bounds__(256) void k_table(
    const float* __restrict__ W1, const float* __restrict__ W2,
    const float* __restrict__ W1f, const float* __restrict__ W2f,
    float* __restrict__ tab)
{
  __shared__ float h[G_TAB][256];
  __shared__ float hf[G_TAB][256];
  const int c = threadIdx.x;
  const int t0 = blockIdx.x * G_TAB;
  const float dr = 2.5f / (float)(T_TAB-1);
  const float w1a = W1[c], w1b = W1[256+c], w1c = W1[512+c];
  const float f1a = W1f[c], f1b = W1f[256+c], f1c = W1f[512+c];
#pragma unroll
  for (int g=0; g<G_TAB; ++g){
    float r = (float)(t0+g) * dr;
    float e0 = soh(r,1.0f), e1 = soh(r,1.5f), e2 = soh(r,2.0f);
    h[g][c]  = fmaxf(e0*w1a + e1*w1b + e2*w1c, 0.0f);
    hf[g][c] = fmaxf(e0*f1a + e1*f1b + e2*f1c, 0.0f);
  }
  __syncthreads();
  for (int j = c; j < 336; j += 256){
    float acc[G_TAB];
#pragma unroll
    for (int g=0; g<G_TAB; ++g) acc[g]=0.0f;
    if (j < 272){
      for (int cc=0; cc<256; ++cc){
        float wv = W2[cc*272 + j];
#pragma unroll
        for (int g=0; g<G_TAB; ++g) acc[g] = fmaf(h[g][cc], wv, acc[g]);
      }
    } else {
      int jj = j - 272;
      for (int cc=0; cc<256; ++cc){
        float wv = W2f[cc*64 + jj];
#pragma unroll
        for (int g=0; g<G_TAB; ++g) acc[g] = fmaf(hf[g][cc], wv, acc[g]);
      }
    }
#pragma unroll
    for (int g=0; g<G_TAB; ++g) tab[(size_t)(t0+g)*336 + j] = acc[g] * 0.0625f;
  }
}

// ---------------- permuted per-lane table: tabP[T_TAB][512] ----------------
__global__ __launch_bounds__(256) void k_perm(
    const float* __restrict__ tab, float* __restrict__ tabP)
{
  const int gid = blockIdx.x*256 + threadIdx.x;     // [0, T_TAB*512)
  const int t = gid >> 9, p = gid & 511;
  int col, slot;
  lane_sched(p>>3, p&7, col, slot);
  tabP[gid] = (col >= 0) ? tab[(size_t)t*336 + col] : 0.0f;
}

// ---------------- rowptr: dst is globally non-decreasing -> CSR via binary search ----
__global__ __launch_bounds__(256) void k_rowptr(
    const int* __restrict__ dst, int E, int* __restrict__ rowptr)
{
  const int n = blockIdx.x*256 + threadIdx.x;
  if (n > NN) return;
  int lo=0, hi=E;
  while (lo < hi){ int mid=(lo+hi)>>1; if (dst[mid] < n) lo=mid+1; else hi=mid; }
  rowptr[n]=lo;
}

// ---------------- x = segsum(sph_harm): 4 lanes/node, each edge touched once -------
__global__ __launch_bounds__(256) void k_x(
    const float* __restrict__ pos, const int* __restrict__ src,
    const int* __restrict__ rowptr, float* __restrict__ xacc)
{
  const int t = blockIdx.x*256 + threadIdx.x;
  const int n = t>>2, q = t&3;
  if (n>=NN) return;
  const int r0=rowptr[n], r1=rowptr[n+1];
  const float pdx=pos[3*n], pdy=pos[3*n+1], pdz=pos[3*n+2];
  const float s3=1.73205081f, s5=2.23606798f, s15=3.87298335f;
  const float c33=2.09165007f, c32=10.2469508f, c31=1.62018517f, c30=1.32287566f, cp2=5.12347538f;
  float a0=0,a1=0,a2=0,a3=0,a4=0,a5=0,a6=0,a7=0,a8=0,a9=0,a10=0,a11=0,a12=0,a13=0,a14=0,a15=0;
  for (int e=r0+q; e<r1; e+=4){
    const int s=src[e];
    float ax=pos[3*s]-pdx, ay=pos[3*s+1]-pdy, az=pos[3*s+2]-pdz;
    float ir = 1.0f/sqrtf(ax*ax+ay*ay+az*az);
    float x=ax*ir, y=ay*ir, z=az*ir;
    a0+=1.0f; a1+=s3*y; a2+=s3*z; a3+=s3*x;
    a4+=s15*x*y; a5+=s15*y*z; a6+=0.5f*s5*(3.0f*z*z-1.0f); a7+=s15*x*z;
    a8+=0.5f*s15*(x*x-y*y); a9+=c33*y*(3.0f*x*x-y*y); a10+=c32*x*y*z; a11+=c31*y*(5.0f*z*z-1.0f);
    a12+=c30*(5.0f*z*z*z-3.0f*z); a13+=c31*x*(5.0f*z*z-1.0f); a14+=cp2*z*(x*x-y*y);
    a15+=c33*x*(x*x-3.0f*y*y);
  }
#define RED(v) v += __shfl_xor(v,1); v += __shfl_xor(v,2);
  RED(a0) RED(a1) RED(a2) RED(a3) RED(a4) RED(a5) RED(a6) RED(a7)
  RED(a8) RED(a9) RED(a10) RED(a11) RED(a12) RED(a13) RED(a14) RED(a15)
#undef RED
  float o0,o1,o2,o3;
  if (q==0){ o0=a0; o1=a1; o2=a2; o3=a3; }
  else if (q==1){ o0=a4; o1=a5; o2=a6; o3=a7; }
  else if (q==2){ o0=a8; o1=a9; o2=a10; o3=a11; }
  else { o0=a12; o1=a13; o2=a14; o3=a15; }
  *(float4*)(xacc + (size_t)n*16 + q*4) = make_float4(o0,o1,o2,o3);
}

// ---------------- fctp1 + gate fused: 4 independent waves per block, 1 node/wave ----
// Phase 1: 4 lanes/edge -> 31 CG intermediates, stored as I*(1-al), I*al in LDS
//          (rows padded to 33 floats: bank = (je+slot)%32, conflict-free).
// Phase 2: 4 coalesced float4 loads/edge from the lane-permuted table tabP,
//          16 conflict-free LDS reads, 16 FMA. Static slot schedule.
// Intra-wave fences only (LDS ops of one wave complete in order).
__global__ __launch_bounds__(256) void k_tp1(
    const float* __restrict__ pos, const int* __restrict__ src,
    const int* __restrict__ rowptr, const float* __restrict__ xacc,
    const float* __restrict__ tabP, float* __restrict__ xg, CGPack cg)
{
  const int wid  = threadIdx.x >> 6;
  const int lane = threadIdx.x & 63;
  const int node = blockIdx.x*4 + wid;
  __shared__ float SIA[4][CH][33];
  __shared__ float SIB[4][CH][33];
  __shared__ int   SiT[4][CH];
  __shared__ float SG[4][32];
  const int r0 = rowptr[node], r1 = rowptr[node+1];
  const int nch = (r1 - r0 + CH - 1) / CH;

#define WAVE_FENCE() { asm volatile("s_waitcnt lgkmcnt(0)" ::: "memory"); __builtin_amdgcn_sched_barrier(0); }

  // ---- static slot schedule (8 slots) + gate indices ----
  int ioS[8];
#pragma unroll
  for (int p=0;p<8;++p){ int c_, s_; lane_sched(lane, p, c_, s_); ioS[p]=s_; }
  int gu0=16, gu1=16;
  if (lane >= 16 && lane < 40){ gu0 = 16 + (lane-16)/3; }
  else if (lane >= 40 && lane < 52){
    int m=lane-40; gu0 = 24 + (2*m)/3; gu1 = 24 + (2*m+1)/3;
  }

  const float pdx=pos[3*node], pdy=pos[3*node+1], pdz=pos[3*node+2];
  const int je = lane & 15, part = lane >> 4;
  float acc0 = 0.f, acc1 = 0.f;

  for (int t=0; t<nch; ++t){
    const int e0 = r0 + t*CH;
    const int cnt = min(CH, r1-e0);
    WAVE_FENCE();                    // WAR: phase-2 reads of prev chunk done
    if (je < cnt){
      const int e = e0 + je;
      const int s = src[e];
      float ax=pos[3*s]-pdx, ay=pos[3*s+1]-pdy, az=pos[3*s+2]-pdz;
      float r = sqrtf(ax*ax+ay*ay+az*az);
      float ir = 1.0f/r;
      float x=ax*ir, y=ay*ir, z=az*ir;
      float f = r * 1638.0f;                    // (T_TAB-1)/2.5
      int i0 = (int)f; if (i0 > T_TAB-2) i0 = T_TAB-2;
      float bl = f - (float)i0;
      float aw = 1.0f - bl;

      const float s3=1.73205081f, s5=2.23606798f, s15=3.87298335f;
      const float c33=2.09165007f, c32=10.2469508f, c31=1.62018517f, c30=1.32287566f, cp2=5.12347538f;
      float Y[16];
      Y[0]=1.0f;
      Y[1]=s3*y; Y[2]=s3*z; Y[3]=s3*x;
      Y[4]=s15*x*y; Y[5]=s15*y*z; Y[6]=0.5f*s5*(3.0f*z*z-1.0f); Y[7]=s15*x*z; Y[8]=0.5f*s15*(x*x-y*y);
      Y[9]=c33*y*(3.0f*x*x-y*y); Y[10]=c32*x*y*z; Y[11]=c31*y*(5.0f*z*z-1.0f);
      Y[12]=c30*(5.0f*z*z*z-3.0f*z); Y[13]=c31*x*(5.0f*z*z-1.0f); Y[14]=cp2*z*(x*x-y*y);
      Y[15]=c33*x*(x*x-3.0f*y*y);
      float X[16];
      {
        const float inv = 0.5129891760f;           // 1/sqrt(3.8)
        const float4* q4 = (const float4*)(xacc + (size_t)s*16);
        float4 a=q4[0],b=q4[1],cc4=q4[2],d4=q4[3];
        X[0]=a.x*inv;X[1]=a.y*inv;X[2]=a.z*inv;X[3]=a.w*inv;
        X[4]=b.x*inv;X[5]=b.y*inv;X[6]=b.z*inv;X[7]=b.w*inv;
        X[8]=cc4.x*inv;X[9]=cc4.y*inv;X[10]=cc4.z*inv;X[11]=cc4.w*inv;
        X[12]=d4.x*inv;X[13]=d4.y*inv;X[14]=d4.z*inv;X[15]=d4.w*inv;
      }
      float* A_ = SIA[wid][je];
      float* B_ = SIB[wid][je];
#define PUT(slot, val) { float vv_=(val); A_[slot]=vv_*aw; B_[slot]=vv_*bl; }
      if (part == 0){
        float t0v = cg.c000[0]*X[0]*Y[0];
        float t1v=0.f, t2v=0.f, t3v=0.f;
#pragma unroll
        for (int i=0;i<3;++i)
#pragma unroll
          for (int j=0;j<3;++j) t1v = fmaf(X[1+i]*Y[1+j], cg.c110[i*3+j], t1v);
#pragma unroll
        for (int i=0;i<5;++i)
#pragma unroll
          for (int j=0;j<5;++j) t2v = fmaf(X[4+i]*Y[4+j], cg.c220[i*5+j], t2v);
#pragma unroll
        for (int i=0;i<7;++i)
#pragma unroll
          for (int j=0;j<7;++j) t3v = fmaf(X[9+i]*Y[9+j], cg.c330[i*7+j], t3v);
        float v12[3]={0,0,0};
#pragma unroll
        for (int i=0;i<3;++i)
#pragma unroll
          for (int j=0;j<5;++j){ float tt=X[1+i]*Y[4+j];
#pragma unroll
            for (int k=0;k<3;++k) v12[k]=fmaf(tt, cg.c121[(i*5+j)*3+k], v12[k]); }
        PUT(0,t0v) PUT(1,t1v) PUT(2,t2v) PUT(3,t3v)
        PUT(10,v12[0]) PUT(11,v12[1]) PUT(12,v12[2])
        A_[31]=0.0f; B_[31]=0.0f;
        SiT[wid][je]=i0;
      } else if (part == 1){
        float v01[3]={0,0,0}, v10[3]={0,0,0}, v33[3]={0,0,0};
#pragma unroll
        for (int j=0;j<3;++j){ float tt=X[0]*Y[1+j];
#pragma unroll
          for (int k=0;k<3;++k) v01[k]=fmaf(tt, cg.c011[j*3+k], v01[k]); }
#pragma unroll
        for (int i=0;i<3;++i){ float tt=X[1+i]*Y[0];
#pragma unroll
          for (int k=0;k<3;++k) v10[k]=fmaf(tt, cg.c101[i*3+k], v10[k]); }
#pragma unroll
        for (int i=0;i<7;++i)
#pragma unroll
          for (int j=0;j<7;++j){ float tt=X[9+i]*Y[9+j];
#pragma unroll
            for (int k=0;k<3;++k) v33[k]=fmaf(tt, cg.c331[(i*7+j)*3+k], v33[k]); }
        PUT(4,v01[0]) PUT(5,v01[1]) PUT(6,v01[2])
        PUT(7,v10[0]) PUT(8,v10[1]) PUT(9,v10[2])
        PUT(28,v33[0]) PUT(29,v33[1]) PUT(30,v33[2])
      } else if (part == 2){
        float v11[3]={0,0,0}, v21[3]={0,0,0}, v23[3]={0,0,0};
#pragma unroll
        for (int i=0;i<3;++i)
#pragma unroll
          for (int j=0;j<3;++j){ float tt=X[1+i]*Y[1+j];
#pragma unroll
            for (int k=0;k<3;++k) v11[k]=fmaf(tt, cg.c111[(i*3+j)*3+k], v11[k]); }
#pragma unroll
        for (int i=0;i<5;++i)
#pragma unroll
          for (int j=0;j<3;++j){ float tt=X[4+i]*Y[1+j];
#pragma unroll
            for (int k=0;k<3;++k) v21[k]=fmaf(tt, cg.c211[(i*3+j)*3+k], v21[k]); }
#pragma unroll
        for (int i=0;i<5;++i)
#pragma unroll
          for (int j=0;j<7;++j){ float tt=X[4+i]*Y[9+j];
#pragma unroll
            for (int k=0;k<3;++k) v23[k]=fmaf(tt, cg.c231[(i*7+j)*3+k], v23[k]); }
        PUT(22,v11[0]) PUT(23,v11[1]) PUT(24,v11[2])
        PUT(13,v21[0]) PUT(14,v21[1]) PUT(15,v21[2])
        PUT(16,v23[0]) PUT(17,v23[1]) PUT(18,v23[2])
      } else {
        float v22[3]={0,0,0}, v32[3]={0,0,0};
#pragma unroll
        for (int i=0;i<5;++i)
#pragma unroll
          for (int j=0;j<5;++j){ float tt=X[4+i]*Y[4+j];
#pragma unroll
            for (int k=0;k<3;++k) v22[k]=fmaf(tt, cg.c221[(i*5+j)*3+k], v22[k]); }
#pragma unroll
        for (int i=0;i<7;++i)
#pragma unroll
          for (int j=0;j<5;++j){ float tt=X[9+i]*Y[4+j];
#pragma unroll
            for (int k=0;k<3;++k) v32[k]=fmaf(tt, cg.c321[(i*5+j)*3+k], v32[k]); }
        PUT(25,v22[0]) PUT(26,v22[1]) PUT(27,v22[2])
        PUT(19,v32[0]) PUT(20,v32[1]) PUT(21,v32[2])
      }
#undef PUT
    }
    WAVE_FENCE();                    // RAW: phase-1 writes visible
    // ---- phase 2: coalesced permuted-table loads, static slots ----
#pragma unroll 4
    for (int j=0; j<CH; ++j){
      if (j < cnt){
        const float* __restrict__ IA = SIA[wid][j];
        const float* __restrict__ IB = SIB[wid][j];
        const float* __restrict__ wp = tabP + ((size_t)SiT[wid][j]*512) + 8*lane;
        float4 wa = *(const float4*)wp;
        float4 wb = *(const float4*)(wp+4);
        float4 wc = *(const float4*)(wp+512);
        float4 wd = *(const float4*)(wp+516);
        acc0 = fmaf(wa.x, IA[ioS[0]], acc0); acc0 = fmaf(wc.x, IB[ioS[0]], acc0);
        acc0 = fmaf(wa.y, IA[ioS[1]], acc0); acc0 = fmaf(wc.y, IB[ioS[1]], acc0);
        acc0 = fmaf(wa.z, IA[ioS[2]], acc0); acc0 = fmaf(wc.z, IB[ioS[2]], acc0);
        acc0 = fmaf(wa.w, IA[ioS[3]], acc0); acc0 = fmaf(wc.w, IB[ioS[3]], acc0);
        acc1 = fmaf(wb.x, IA[ioS[4]], acc1); acc1 = fmaf(wd.x, IB[ioS[4]], acc1);
        acc1 = fmaf(wb.y, IA[ioS[5]], acc1); acc1 = fmaf(wd.y, IB[ioS[5]], acc1);
        acc1 = fmaf(wb.z, IA[ioS[6]], acc1); acc1 = fmaf(wd.z, IB[ioS[6]], acc1);
        acc1 = fmaf(wb.w, IA[ioS[7]], acc1); acc1 = fmaf(wd.w, IB[ioS[7]], acc1);
      }
    }
  }

  // ---- fused gate epilogue ----
  const float inv = 0.5129891760f;
  if (lane < 16){
    SG[wid][2*lane]   = acc0*0.5f*inv;
    SG[wid][2*lane+1] = acc1*0.5f*inv;
  }
  WAVE_FENCE();
  float* __restrict__ o = xg + (size_t)node*64;
  if (lane < 16){
    o[lane] = fmaxf(SG[wid][lane], 0.0f);                  // se
  } else if (lane < 40){
    int idx = lane-16;
    float vv = (acc0+acc1)*0.4082482905f*inv;
    o[16+idx] = vv * fmaxf(SG[wid][gu0], 0.0f);            // v1o (u<8)
  } else if (lane < 52){
    int m = lane-40;
    float vv0 = acc0*0.5773502692f*inv;
    float vv1 = acc1*0.5773502692f*inv;
    o[40+2*m]   = vv0 * fmaxf(SG[wid][gu0], 0.0f);         // v1e (u<8)
    o[40+2*m+1] = vv1 * fmaxf(SG[wid][gu1], 0.0f);
  }
#undef WAVE_FENCE
}

// ---------------- fctp2 per edge -> e2buf[E][4] (pruned) ----------------
__global__ __launch_bounds__(256) void k_tp2(
    const float* __restrict__ pos, const int* __restrict__ src, const int* __restrict__ dst, int E,
    const float* __restrict__ xg, const float* __restrict__ tab,
    float* __restrict__ e2buf, CGPack cg)
{
  const int e = blockIdx.x*256 + threadIdx.x;
  if (e>=E) return;
  const int s = src[e], d = dst[e];
  float ax=pos[3*s]-pos[3*d], ay=pos[3*s+1]-pos[3*d+1], az=pos[3*s+2]-pos[3*d+2];
  float r = sqrtf(ax*ax+ay*ay+az*az);
  float ir = 1.0f/r;
  float x=ax*ir, y=ay*ir, z=az*ir;
  float f = r * 1638.0f;
  int i0 = (int)f; if (i0 > T_TAB-2) i0 = T_TAB-2;
  const float al = f - (float)i0;
  const float* __restrict__ w0 = tab + (size_t)i0*336 + 272;
  const float* __restrict__ w1 = w0 + 336;
  float wse[16], wA[8], wB[8], wC[8];
#pragma unroll
  for (int j=0;j<16;j+=4){
    float4 p = *(const float4*)(w0+j);
    float4 q = *(const float4*)(w1+j);
    wse[j+0]=fmaf(al,q.x-p.x,p.x); wse[j+1]=fmaf(al,q.y-p.y,p.y);
    wse[j+2]=fmaf(al,q.z-p.z,p.z); wse[j+3]=fmaf(al,q.w-p.w,p.w);
  }
#pragma unroll
  for (int j=0;j<8;j+=4){
    float4 p = *(const float4*)(w0+16+j); float4 q = *(const float4*)(w1+16+j);
    wA[j+0]=fmaf(al,q.x-p.x,p.x); wA[j+1]=fmaf(al,q.y-p.y,p.y);
    wA[j+2]=fmaf(al,q.z-p.z,p.z); wA[j+3]=fmaf(al,q.w-p.w,p.w);
    p = *(const float4*)(w0+32+j); q = *(const float4*)(w1+32+j);
    wB[j+0]=fmaf(al,q.x-p.x,p.x); wB[j+1]=fmaf(al,q.y-p.y,p.y);
    wB[j+2]=fmaf(al,q.z-p.z,p.z); wB[j+3]=fmaf(al,q.w-p.w,p.w);
    p = *(const float4*)(w0+48+j); q = *(const float4*)(w1+48+j);
    wC[j+0]=fmaf(al,q.x-p.x,p.x); wC[j+1]=fmaf(al,q.y-p.y,p.y);
    wC[j+2]=fmaf(al,q.z-p.z,p.z); wC[j+3]=fmaf(al,q.w-p.w,p.w);
  }
  const float s3=1.73205081f, s5=2.23606798f, s15=3.87298335f;
  float Y[9];
  Y[0]=1.0f;
  Y[1]=s3*y; Y[2]=s3*z; Y[3]=s3*x;
  Y[4]=s15*x*y; Y[5]=s15*y*z; Y[6]=0.5f*s5*(3.0f*z*z-1.0f); Y[7]=s15*x*z; Y[8]=0.5f*s15*(x*x-y*y);
  const float* __restrict__ g = xg + (size_t)s*64;
  float se[16], vo[24], ve[24];
#pragma unroll
  for (int jj=0;jj<4;++jj){ float4 t=((const float4*)g)[jj];
    se[4*jj]=t.x; se[4*jj+1]=t.y; se[4*jj+2]=t.z; se[4*jj+3]=t.w; }
#pragma unroll
  for (int jj=0;jj<6;++jj){ float4 t=((const float4*)(g+16))[jj];
    vo[4*jj]=t.x; vo[4*jj+1]=t.y; vo[4*jj+2]=t.z; vo[4*jj+3]=t.w; }
#pragma unroll
  for (int jj=0;jj<6;++jj){ float4 t=((const float4*)(g+40))[jj];
    ve[4*jj]=t.x; ve[4*jj+1]=t.y; ve[4*jj+2]=t.z; ve[4*jj+3]=t.w; }

  float SA=0.0f;
#pragma unroll
  for (int u=0;u<16;++u) SA = fmaf(wse[u], se[u], SA);
  float AB[3]={0,0,0}, AC[3]={0,0,0}, AD[3]={0,0,0};
#pragma unroll
  for (int u=0;u<8;++u)
#pragma unroll
    for (int i=0;i<3;++i){
      AB[i]=fmaf(wA[u], vo[u*3+i], AB[i]);
      AC[i]=fmaf(wB[u], vo[u*3+i], AC[i]);
      AD[i]=fmaf(wC[u], ve[u*3+i], AD[i]);
    }
  float e2[3]={0,0,0};
#pragma unroll
  for (int j=0;j<3;++j){ float t=SA*Y[1+j];
#pragma unroll
    for (int k=0;k<3;++k) e2[k]=fmaf(t, cg.c011[j*3+k], e2[k]); }
#pragma unroll
  for (int i=0;i<3;++i){ float t=AB[i]*Y[0];
#pragma unroll
    for (int k=0;k<3;++k) e2[k]=fmaf(t, cg.c101[i*3+k], e2[k]); }
#pragma unroll
  for (int i=0;i<3;++i)
#pragma unroll
    for (int j=0;j<5;++j){ float t=AC[i]*Y[4+j];
#pragma unroll
      for (int k=0;k<3;++k) e2[k]=fmaf(t, cg.c121[(i*5+j)*3+k], e2[k]); }
#pragma unroll
  for (int i=0;i<3;++i)
#pragma unroll
    for (int j=0;j<3;++j){ float t=AD[i]*Y[1+j];
#pragma unroll
      for (int k=0;k<3;++k) e2[k]=fmaf(t, cg.c111[(i*3+j)*3+k], e2[k]); }

  *(float4*)(e2buf + (size_t)e*4) = make_float4(e2[0], e2[1], e2[2], 0.0f);
}

// ---------------- final gather ----------------
__global__ __launch_bounds__(256) void k_out(
    const float* __restrict__ e2buf, const int* __restrict__ rowptr,
    float* __restrict__ out)
{
  const int t = blockIdx.x*256 + threadIdx.x;
  const int n = t>>2, k = t&3;
  if (n>=NN) return;
  const int r0=rowptr[n], r1=rowptr[n+1];
  float a=0.f;
  for (int e=r0;e<r1;++e) a += e2buf[(size_t)e*4 + k];
  const float sc = 0.0641236437f;  // (1/sqrt(64)) * 1/sqrt(3.8)
  if (k<3) out[(size_t)n*3 + k] = a*sc;
}

// ---------------- host launcher ----------------
extern "C" void kernel_launch(void* const* d_in, const int* in_sizes, int n_in,
                              void* d_out, int out_size, void* d_ws, size_t ws_size,
                              hipStream_t stream)
{
  (void)n_in; (void)ws_size; (void)out_size;
  const float* pos = (const float*)d_in[0];
  const int*   src = (const int*)d_in[1];
  const int*   dst = (const int*)d_in[2];
  const float* W1  = (const float*)d_in[3];
  const float* W2  = (const float*)d_in[4];
  const float* W1f = (const float*)d_in[5];
  const float* W2f = (const float*)d_in[6];
  const int E = in_sizes[1];

  char* ws = (char*)d_ws;
  float* xacc  = (float*)ws;                     // NN*16
  float* xg    = xacc + (size_t)NN*16;           // NN*64
  float* tab   = xg + (size_t)NN*64;             // T_TAB*336
  float* tabP  = tab + (size_t)T_TAB*336;        // T_TAB*512
  float* e2buf = tabP + (size_t)T_TAB*512;       // E*4
  int*   rowptr= (int*)(e2buf + (size_t)E*4);    // NN+1

  CGPack cg;
  build_cg(cg);

  k_table<<<T_TAB/G_TAB, 256, 0, stream>>>(W1, W2, W1f, W2f, tab);
  k_perm<<<(T_TAB*512)/256, 256, 0, stream>>>(tab, tabP);
  k_rowptr<<<(NN+1+255)/256, 256, 0, stream>>>(dst, E, rowptr);
  k_x<<<(NN*4)/256, 256, 0, stream>>>(pos, src, rowptr, xacc);
  k_tp1<<<NN/4, 256, 0, stream>>>(pos, src, rowptr, xacc, tabP, xg, cg);
  k_tp2<<<(E + 255) / 256, 256, 0, stream>>>(pos, src, dst, E, xg, tab, e2buf, cg);
  k_out<<<(NN*4)/256, 256, 0, stream>>>(e2buf, rowptr, (float*)d_out);
}